// Round 1
// baseline (2561.677 us; speedup 1.0000x reference)
//
#include <hip/hip_runtime.h>

#define U_CNT 50000
#define I_CNT 100000
#define DIM 64
#define E_CNT 4000000
#define N_CNT (U_CNT + I_CNT)

// ego = concat(user, item); acc = ego  (float4 vectorized; U*D divisible by 4)
__global__ __launch_bounds__(256) void init_kernel(
    const float* __restrict__ user_emb,
    const float* __restrict__ item_emb,
    float* __restrict__ ego,
    float* __restrict__ acc)
{
    long idx = (long)blockIdx.x * blockDim.x + threadIdx.x;   // float4 index
    const long total = (long)N_CNT * DIM / 4;
    if (idx >= total) return;
    long f = idx * 4;
    const long ubound = (long)U_CNT * DIM;
    float4 v;
    if (f < ubound) v = *(const float4*)(user_emb + f);
    else            v = *(const float4*)(item_emb + (f - ubound));
    ((float4*)ego)[idx] = v;
    ((float4*)acc)[idx] = v;
}

// COO SpMM: y[r,:] += val * x[c,:]  — one wave (64 lanes) per edge, lane = dim
__global__ __launch_bounds__(256) void spmm_atomic(
    const int*   __restrict__ rows,
    const int*   __restrict__ cols,
    const float* __restrict__ vals,
    const float* __restrict__ x,
    float*       __restrict__ y)
{
    const int lane = threadIdx.x & 63;
    long wave  = ((long)blockIdx.x * blockDim.x + threadIdx.x) >> 6;
    long nwave = ((long)gridDim.x * blockDim.x) >> 6;
    for (long e = wave; e < E_CNT; e += nwave) {
        int   r = rows[e];
        int   c = cols[e];
        float v = vals[e];
        float xv = x[(long)c * DIM + lane];
        atomicAdd(&y[(long)r * DIM + lane], v * xv);
    }
}

// acc = (acc + layer) * scale   (float4 vectorized)
__global__ __launch_bounds__(256) void acc_add_scale(
    const float* __restrict__ layer,
    float* __restrict__ acc,
    float scale)
{
    long idx = (long)blockIdx.x * blockDim.x + threadIdx.x;
    const long total = (long)N_CNT * DIM / 4;
    if (idx >= total) return;
    float4 a = ((const float4*)acc)[idx];
    float4 b = ((const float4*)layer)[idx];
    a.x = (a.x + b.x) * scale;
    a.y = (a.y + b.y) * scale;
    a.z = (a.z + b.z) * scale;
    a.w = (a.w + b.w) * scale;
    ((float4*)acc)[idx] = a;
}

extern "C" void kernel_launch(void* const* d_in, const int* in_sizes, int n_in,
                              void* d_out, int out_size, void* d_ws, size_t ws_size,
                              hipStream_t stream) {
    const float* user_emb = (const float*)d_in[0];
    const float* item_emb = (const float*)d_in[1];
    const int*   rows     = (const int*)d_in[2];
    const int*   cols     = (const int*)d_in[3];
    const float* vals     = (const float*)d_in[4];
    float* acc = (float*)d_out;                 // [N, D] accumulator / final output

    float* ego = (float*)d_ws;                  // [N, D]
    float* nxt = ego + (long)N_CNT * DIM;       // [N, D]

    const long total_f4 = (long)N_CNT * DIM / 4;
    const int  vb = 256;
    const int  vgrid = (int)((total_f4 + vb - 1) / vb);

    init_kernel<<<vgrid, vb, 0, stream>>>(user_emb, item_emb, ego, acc);

    const size_t layer_bytes = (size_t)N_CNT * DIM * sizeof(float);
    const int spmm_blocks = 2048;   // grid-stride, 4 waves/block

    for (int l = 0; l < 3; ++l) {
        hipMemsetAsync(nxt, 0, layer_bytes, stream);
        spmm_atomic<<<spmm_blocks, 256, 0, stream>>>(rows, cols, vals, ego, nxt);
        float scale = (l == 2) ? 0.25f : 1.0f;
        acc_add_scale<<<vgrid, vb, 0, stream>>>(nxt, acc, scale);
        float* tmp = ego; ego = nxt; nxt = tmp;
    }
}

// Round 2
// 956.151 us; speedup vs baseline: 2.6792x; 2.6792x over previous
//
#include <hip/hip_runtime.h>

#define U_CNT 50000
#define I_CNT 100000
#define DIM 64
#define E_CNT 4000000
#define N_CNT (U_CNT + I_CNT)
#define SCAN_BLK 256
#define NBLK_SCAN ((N_CNT + SCAN_BLK - 1) / SCAN_BLK)   // 586

typedef unsigned long long u64;
typedef unsigned int u32;

// ego = concat(user, item); acc = ego  (float4 vectorized; U*D divisible by 4)
__global__ __launch_bounds__(256) void init_kernel(
    const float* __restrict__ user_emb,
    const float* __restrict__ item_emb,
    float* __restrict__ ego,
    float* __restrict__ acc)
{
    long idx = (long)blockIdx.x * blockDim.x + threadIdx.x;   // float4 index
    const long total = (long)N_CNT * DIM / 4;
    if (idx >= total) return;
    long f = idx * 4;
    const long ubound = (long)U_CNT * DIM;
    float4 v;
    if (f < ubound) v = *(const float4*)(user_emb + f);
    else            v = *(const float4*)(item_emb + (f - ubound));
    ((float4*)ego)[idx] = v;
    ((float4*)acc)[idx] = v;
}

// cnt[r]++ for each edge
__global__ __launch_bounds__(256) void hist_kernel(
    const int* __restrict__ rows, int* __restrict__ cnt)
{
    long stride = (long)gridDim.x * blockDim.x;
    for (long e = (long)blockIdx.x * blockDim.x + threadIdx.x; e < E_CNT; e += stride)
        atomicAdd(&cnt[rows[e]], 1);
}

// per-block sums of cnt → partial[b]
__global__ __launch_bounds__(SCAN_BLK) void partial_sum_kernel(
    const int* __restrict__ cnt, int* __restrict__ partial)
{
    __shared__ int sm[SCAN_BLK];
    int i = blockIdx.x * SCAN_BLK + threadIdx.x;
    sm[threadIdx.x] = (i < N_CNT) ? cnt[i] : 0;
    __syncthreads();
    for (int off = SCAN_BLK / 2; off > 0; off >>= 1) {
        if (threadIdx.x < off) sm[threadIdx.x] += sm[threadIdx.x + off];
        __syncthreads();
    }
    if (threadIdx.x == 0) partial[blockIdx.x] = sm[0];
}

// exclusive scan of partial[0..NBLK_SCAN) in one block (1024 threads, Hillis-Steele)
__global__ __launch_bounds__(1024) void scan_partial_kernel(int* __restrict__ partial)
{
    __shared__ int sm[1024];
    int tid = threadIdx.x;
    int v = (tid < NBLK_SCAN) ? partial[tid] : 0;
    sm[tid] = v;
    __syncthreads();
    for (int off = 1; off < 1024; off <<= 1) {
        int t = (tid >= off) ? sm[tid - off] : 0;
        __syncthreads();
        sm[tid] += t;
        __syncthreads();
    }
    if (tid < NBLK_SCAN) partial[tid] = sm[tid] - v;   // exclusive
}

// final scan: row_start[i] = global exclusive prefix; cnt[i] = same (scatter cursor)
__global__ __launch_bounds__(SCAN_BLK) void scan_final_kernel(
    int* __restrict__ cnt, const int* __restrict__ partial, int* __restrict__ row_start)
{
    __shared__ int sm[SCAN_BLK];
    int tid = threadIdx.x;
    int i = blockIdx.x * SCAN_BLK + tid;
    int v = (i < N_CNT) ? cnt[i] : 0;
    sm[tid] = v;
    __syncthreads();
    for (int off = 1; off < SCAN_BLK; off <<= 1) {
        int t = (tid >= off) ? sm[tid - off] : 0;
        __syncthreads();
        sm[tid] += t;
        __syncthreads();
    }
    int excl = partial[blockIdx.x] + sm[tid] - v;
    if (i < N_CNT) {
        row_start[i] = excl;
        cnt[i] = excl;                       // becomes scatter cursor
        if (i == N_CNT - 1) row_start[N_CNT] = E_CNT;
    }
}

// pck[pos] = {val:hi32, col:lo32}, pos = cursor[row]++
__global__ __launch_bounds__(256) void scatter_kernel(
    const int* __restrict__ rows, const int* __restrict__ cols,
    const float* __restrict__ vals, int* __restrict__ cursor,
    u64* __restrict__ pck)
{
    long stride = (long)gridDim.x * blockDim.x;
    for (long e = (long)blockIdx.x * blockDim.x + threadIdx.x; e < E_CNT; e += stride) {
        int r = rows[e];
        int p = atomicAdd(&cursor[r], 1);
        u64 packed = ((u64)__float_as_uint(vals[e]) << 32) | (u32)cols[e];
        pck[p] = packed;
    }
}

// Pull CSR SpMM, one wave per row, lane = dim. Fused acc update.
// y[r,lane] = sum_e val_e * x[col_e*64+lane];  out += y  (×0.25 on last layer)
__global__ __launch_bounds__(256) void spmm_csr(
    const int* __restrict__ row_start,
    const u64* __restrict__ pck,
    const float* __restrict__ x,
    float* __restrict__ y,
    float* __restrict__ outacc,
    int last)
{
    const int lane = threadIdx.x & 63;
    int r = (int)(((long)blockIdx.x * blockDim.x + threadIdx.x) >> 6);
    if (r >= N_CNT) return;
    int s = row_start[r];
    int e = row_start[r + 1];
    float a0 = 0.f, a1 = 0.f, a2 = 0.f, a3 = 0.f;
    for (int base = s; base < e; base += 64) {
        int cnt = min(64, e - base);
        u64 pk = (base + lane < e) ? pck[base + lane] : 0ULL;
        int j = 0;
        for (; j + 4 <= cnt; j += 4) {
            u64 p0 = __shfl(pk, j);
            u64 p1 = __shfl(pk, j + 1);
            u64 p2 = __shfl(pk, j + 2);
            u64 p3 = __shfl(pk, j + 3);
            float x0 = x[(long)(u32)p0 * DIM + lane];
            float x1 = x[(long)(u32)p1 * DIM + lane];
            float x2 = x[(long)(u32)p2 * DIM + lane];
            float x3 = x[(long)(u32)p3 * DIM + lane];
            a0 = fmaf(__uint_as_float((u32)(p0 >> 32)), x0, a0);
            a1 = fmaf(__uint_as_float((u32)(p1 >> 32)), x1, a1);
            a2 = fmaf(__uint_as_float((u32)(p2 >> 32)), x2, a2);
            a3 = fmaf(__uint_as_float((u32)(p3 >> 32)), x3, a3);
        }
        for (; j < cnt; ++j) {
            u64 p0 = __shfl(pk, j);
            float x0 = x[(long)(u32)p0 * DIM + lane];
            a0 = fmaf(__uint_as_float((u32)(p0 >> 32)), x0, a0);
        }
    }
    float acc = (a0 + a1) + (a2 + a3);
    long o = (long)r * DIM + lane;
    y[o] = acc;
    float t = outacc[o] + acc;
    outacc[o] = last ? t * 0.25f : t;
}

extern "C" void kernel_launch(void* const* d_in, const int* in_sizes, int n_in,
                              void* d_out, int out_size, void* d_ws, size_t ws_size,
                              hipStream_t stream) {
    const float* user_emb = (const float*)d_in[0];
    const float* item_emb = (const float*)d_in[1];
    const int*   rows     = (const int*)d_in[2];
    const int*   cols     = (const int*)d_in[3];
    const float* vals     = (const float*)d_in[4];
    float* outacc = (float*)d_out;               // [N, D]

    // workspace layout (8B-aligned first)
    char* ws = (char*)d_ws;
    u64*  pck       = (u64*)ws;                                 ws += (size_t)E_CNT * 8;
    float* ego      = (float*)ws;                               ws += (size_t)N_CNT * DIM * 4;
    float* nxt      = (float*)ws;                               ws += (size_t)N_CNT * DIM * 4;
    int*  cnt       = (int*)ws;                                 ws += (size_t)N_CNT * 4;
    int*  row_start = (int*)ws;                                 ws += (size_t)(N_CNT + 2) * 4;
    int*  partial   = (int*)ws;                                 ws += 1024 * 4;

    const long total_f4 = (long)N_CNT * DIM / 4;
    const int  vgrid = (int)((total_f4 + 255) / 256);

    hipMemsetAsync(cnt, 0, (size_t)N_CNT * 4, stream);
    init_kernel<<<vgrid, 256, 0, stream>>>(user_emb, item_emb, ego, outacc);

    hist_kernel<<<2048, 256, 0, stream>>>(rows, cnt);
    partial_sum_kernel<<<NBLK_SCAN, SCAN_BLK, 0, stream>>>(cnt, partial);
    scan_partial_kernel<<<1, 1024, 0, stream>>>(partial);
    scan_final_kernel<<<NBLK_SCAN, SCAN_BLK, 0, stream>>>(cnt, partial, row_start);
    scatter_kernel<<<2048, 256, 0, stream>>>(rows, cols, vals, cnt, pck);

    const int spmm_grid = (N_CNT * 64 + 255) / 256;   // one wave per row
    for (int l = 0; l < 3; ++l) {
        spmm_csr<<<spmm_grid, 256, 0, stream>>>(row_start, pck, ego, nxt, outacc, l == 2);
        float* tmp = ego; ego = nxt; nxt = tmp;
    }
}